// Round 4
// baseline (773.561 us; speedup 1.0000x reference)
//
#include <hip/hip_runtime.h>

// y[n,o,m] = alpha * sum_i x[n,i,m] * K[irr(m),i,o]
// N=50000 nodes, MUL_IN=MUL_OUT=128, DIM_TOTAL=9, irr: m=0->0, m=1..3->1, m=4..8->2
//
// Block: 256 threads (4 waves), 16 nodes/block (50000 = 16*3125, no tail).
//   n = tid&15 -> node; q = (tid>>4)&3, w = tid>>6 -> obase = w*32+q*8 (8 o's/thread)
//   acc[9][8] per thread, i-loop in 4 chunks of 32, x chunk staged in LDS (24 KB).
// Occupancy: ~130 VGPR -> 3 waves/SIMD -> 3 blocks/CU; staging of one block
// overlaps compute of the others (the 512-thread version fit only 1 block/CU).
// LDS layout xs[ii][node][m pad 12]: 48B node stride -> 16B-group (3n)%8, 16
// distinct addrs over 64 lanes -> worst 2-way conflict (free) on ds_read_b128.

#define NODES_PER_BLOCK 16
#define THREADS 256
#define CHUNK_I 32
#define N_CHUNKS 4
#define MPAD 12

#define FMA_ROW(m, xval, ka, kb_)                                     \
    acc[m][0] += (xval) * (ka).x;  acc[m][1] += (xval) * (ka).y;      \
    acc[m][2] += (xval) * (ka).z;  acc[m][3] += (xval) * (ka).w;      \
    acc[m][4] += (xval) * (kb_).x; acc[m][5] += (xval) * (kb_).y;     \
    acc[m][6] += (xval) * (kb_).z; acc[m][7] += (xval) * (kb_).w;

__global__ __launch_bounds__(THREADS)
void aligned_linear_kernel(const float* __restrict__ x,
                           const float* __restrict__ kern,
                           float* __restrict__ out,
                           int n_nodes) {
    __shared__ float xs[CHUNK_I * NODES_PER_BLOCK * MPAD];  // 24576 B

    const int tid   = threadIdx.x;
    const int node0 = blockIdx.x * NODES_PER_BLOCK;

    const int n     = tid & 15;          // node lane
    const int q     = (tid >> 4) & 3;    // o-quarter within wave
    const int w     = tid >> 6;          // wave id 0..3
    const int obase = w * 32 + q * 8;    // this thread's 8 consecutive o's

    float acc[9][8];
#pragma unroll
    for (int m = 0; m < 9; ++m)
#pragma unroll
        for (int j = 0; j < 8; ++j) acc[m][j] = 0.0f;

    const int  node    = node0 + n;
    const bool node_ok = node < n_nodes;

    for (int c = 0; c < N_CHUNKS; ++c) {
        __syncthreads();
        // ---- stage chunk c: 16 nodes x (32 i x 9 m) floats, coalesced float4 reads ----
        for (int u = tid; u < NODES_PER_BLOCK * 72; u += THREADS) {
            const int nl = u / 72;        // local node
            const int e4 = u % 72;        // float4 index in node's 288-float chunk row
            const int gnode = node0 + nl;
            float4 v = make_float4(0.0f, 0.0f, 0.0f, 0.0f);
            if (gnode < n_nodes)
                v = *reinterpret_cast<const float4*>(
                        x + (size_t)gnode * 1152 + c * 288 + e4 * 4);
            const int e = e4 * 4;
#pragma unroll
            for (int r = 0; r < 4; ++r) {
                const int ii = (e + r) / 9;
                const int m  = (e + r) % 9;
                xs[ii * (NODES_PER_BLOCK * MPAD) + nl * MPAD + m] = (&v.x)[r];
            }
        }
        __syncthreads();

        // ---- compute 32 i-steps ----
        const float* kb = kern + (size_t)(c * CHUNK_I) * 128 + obase;
        for (int ii = 0; ii < CHUNK_I; ++ii) {
            const float* kr = kb + ii * 128;
            // K rows for the 3 irreps, 8 o's each (quarter-wave-uniform, L1-hot)
            const float4 k0a = *reinterpret_cast<const float4*>(kr);
            const float4 k0b = *reinterpret_cast<const float4*>(kr + 4);
            const float4 k1a = *reinterpret_cast<const float4*>(kr + 16384);
            const float4 k1b = *reinterpret_cast<const float4*>(kr + 16384 + 4);
            const float4 k2a = *reinterpret_cast<const float4*>(kr + 32768);
            const float4 k2b = *reinterpret_cast<const float4*>(kr + 32768 + 4);

            const float4* xr = reinterpret_cast<const float4*>(xs)
                               + ii * (NODES_PER_BLOCK * MPAD / 4) + n * 3;
            const float4 xv0 = xr[0];  // m 0..3
            const float4 xv1 = xr[1];  // m 4..7
            const float4 xv2 = xr[2];  // m 8 (.x), rest pad

            FMA_ROW(0, xv0.x, k0a, k0b)
            FMA_ROW(1, xv0.y, k1a, k1b)
            FMA_ROW(2, xv0.z, k1a, k1b)
            FMA_ROW(3, xv0.w, k1a, k1b)
            FMA_ROW(4, xv1.x, k2a, k2b)
            FMA_ROW(5, xv1.y, k2a, k2b)
            FMA_ROW(6, xv1.z, k2a, k2b)
            FMA_ROW(7, xv1.w, k2a, k2b)
            FMA_ROW(8, xv2.x, k2a, k2b)
        }
    }

    // ---- epilogue: thread owns contiguous 288 B of y; repack to float4 stores ----
    if (node_ok) {
        const float alpha = 0.088388347648318447f;  // sqrt(1/128)
        float* yb = out + (size_t)node * 1152 + obase * 9;  // 16B-aligned
#pragma unroll
        for (int f = 0; f < 18; ++f) {
            float4 v;
#pragma unroll
            for (int r = 0; r < 4; ++r) {
                const int idx = f * 4 + r;        // flat j*9+m, compile-time
                (&v.x)[r] = alpha * acc[idx % 9][idx / 9];
            }
            *reinterpret_cast<float4*>(yb + f * 4) = v;
        }
    }
}

extern "C" void kernel_launch(void* const* d_in, const int* in_sizes, int n_in,
                              void* d_out, int out_size, void* d_ws, size_t ws_size,
                              hipStream_t stream) {
    const float* x    = (const float*)d_in[0];
    const float* kern = (const float*)d_in[1];
    float*       out  = (float*)d_out;
    const int n_nodes = in_sizes[0] / 1152;
    const int blocks  = (n_nodes + NODES_PER_BLOCK - 1) / NODES_PER_BLOCK;
    hipLaunchKernelGGL(aligned_linear_kernel, dim3(blocks), dim3(THREADS), 0, stream,
                       x, kern, out, n_nodes);
}